// Round 5
// baseline (273.161 us; speedup 1.0000x reference)
//
#include <hip/hip_runtime.h>

// VQ nearest-neighbor via fp16 split-GEMM on MFMA.
// z_e [B,D] f32, codebook [K,D] f32 -> z_q [B,D] f32, indices [B] (as f32)
// argmin_k ||z-c_k|| == argmin_k (c_sq[k] - 2*z.c_k)
// cross = Zh.Ch + Zh.Cl + Zl.Ch (fp32 MFMA accum; dropped Zl.Cl ~ 2^-22 rel)
// Round 5: NO LDS, NO barriers. Prep writes fragment-contiguous images; every
// MFMA fragment is one coalesced 1KB global_load_dwordx4 (L2-resident).
// B-frags reg-double-buffered; waves free-run; 2 waves/SIMD hide L2 latency.

constexpr int Bn = 8192;
constexpr int Kn = 8192;
constexpr int Dn = 512;

#define SLOTS 16

using half8  = __attribute__((ext_vector_type(8)))  _Float16;
using f32x16 = __attribute__((ext_vector_type(16))) float;

// workspace layout (bytes); images are 8MB each, total 34MB
#define WS_CSQ  0u
#define WS_PART (32u * 1024u)
#define WS_ZH   (2u * 1024u * 1024u)
#define WS_ZL   (10u * 1024u * 1024u)
#define WS_CH   (18u * 1024u * 1024u)
#define WS_CL   (26u * 1024u * 1024u)

// Fragment-contiguous image layout (16B chunk index -> source element):
//   A (Z): tile = rowblk*32 + kt  (4KB tiles: 128 rows x 16 k)
//          chunk c in [0,256): grp=c>>6, kh=(c>>5)&1, r=c&31
//          row = rowblk*128 + grp*32 + r, col = kt*16 + kh*8 .. +7
//   B (C): tile = colblk*32 + kt  (8KB tiles: 256 rows x 16 k), c in [0,512)
//          row = colblk*256 + grp*32 + r  (grp in [0,8))
// An MFMA fragment (64 lanes x 16B, lane = kh*32 + r) is bytes
// [tile*TS + grp*1024, +1KB) -- one contiguous global_load_dwordx4 per frag.

// ---------------- prep: fp32 -> (h,l) fp16 fragment images ----------------
__global__ __launch_bounds__(256) void prep_kernel(const float* __restrict__ Z,
                                                   const float* __restrict__ Cb,
                                                   char* __restrict__ ws) {
  const int gid = blockIdx.x * 256 + threadIdx.x;  // 2 * 524288 16B-chunks
  const int mat = gid >> 19;                       // 0=Z, 1=C
  const int cid = gid & 524287;
  int row, col;
  if (mat == 0) {
    const int tile = cid >> 8, c = cid & 255;
    row = (tile >> 5) * 128 + ((c >> 6) << 5) + (c & 31);
    col = ((tile & 31) << 4) + (((c >> 5) & 1) << 3);
  } else {
    const int tile = cid >> 9, c = cid & 511;
    row = (tile >> 5) * 256 + ((c >> 6) << 5) + (c & 31);
    col = ((tile & 31) << 4) + (((c >> 5) & 1) << 3);
  }
  const float* src = (mat ? Cb : Z) + (size_t)row * Dn + col;
  const float4 v0 = *reinterpret_cast<const float4*>(src);
  const float4 v1 = *reinterpret_cast<const float4*>(src + 4);
  const float f[8] = {v0.x, v0.y, v0.z, v0.w, v1.x, v1.y, v1.z, v1.w};
  _Float16 h[8], l[8];
#pragma unroll
  for (int j = 0; j < 8; ++j) {
    h[j] = (_Float16)f[j];
    l[j] = (_Float16)(f[j] - (float)h[j]);
  }
  const half8 vh = {h[0], h[1], h[2], h[3], h[4], h[5], h[6], h[7]};
  const half8 vl = {l[0], l[1], l[2], l[3], l[4], l[5], l[6], l[7]};
  char* hb = ws + (mat ? WS_CH : WS_ZH);
  char* lb = ws + (mat ? WS_CL : WS_ZL);
  *reinterpret_cast<half8*>(hb + (size_t)cid * 16) = vh;
  *reinterpret_cast<half8*>(lb + (size_t)cid * 16) = vl;
}

// ---------------- c_sq[k] (fp32 exact, deterministic) ----------------
__global__ __launch_bounds__(256) void csq_kernel(const float* __restrict__ C,
                                                  float* __restrict__ csq) {
  const int wave = threadIdx.x >> 6;
  const int lane = threadIdx.x & 63;
  const int row = blockIdx.x * 4 + wave;
  const float4* p = reinterpret_cast<const float4*>(C + (size_t)row * Dn);
  float s = 0.f;
#pragma unroll
  for (int r = 0; r < 2; ++r) {
    float4 v = p[lane * 2 + r];
    s += v.x * v.x + v.y * v.y + v.z * v.z + v.w * v.w;
  }
#pragma unroll
  for (int off = 32; off; off >>= 1) s += __shfl_xor(s, off);
  if (lane == 0) csq[row] = s;
}

// ---------------- MFMA GEMM + fused argmin, all-register, barrier-free ------
// grid = 64 rowblks * 8 splits = 512 blocks, 256 threads (4 waves 2x2), 2/CU.
// Wave tile 64x128, BK=16; u = 0..127 steps (4 panels x 32 k-tiles).
__global__ __launch_bounds__(256, 2) void vq_mfma(const char* __restrict__ ws,
                                                  const float* __restrict__ csq,
                                                  float2* __restrict__ partials) {
  const int t = threadIdx.x;
  const int lane = t & 63;
  const int w = t >> 6;
  const int wm = w >> 1, wn = w & 1;
  const int rowblk = blockIdx.x >> 3;
  const int split = blockIdx.x & 7;  // -> XCD affinity: B panel L2-resident
  const int r31 = lane & 31;
  const int kh = lane >> 5;

  const char* ZH = ws + WS_ZH;
  const char* ZL = ws + WS_ZL;
  const char* CH = ws + WS_CH;
  const char* CL = ws + WS_CL;

  const size_t abase = (size_t)rowblk * 32 * 4096 + (size_t)(wm * 2) * 1024 + lane * 16;
  const size_t bbase = (size_t)(wn * 4) * 1024 + lane * 16;

  // preload all 16 csq values this lane ever needs (static-indexed regs)
  float cs[16];
#pragma unroll
  for (int p = 0; p < 4; ++p)
#pragma unroll
    for (int ns = 0; ns < 4; ++ns)
      cs[p * 4 + ns] = csq[split * 1024 + p * 256 + wn * 128 + ns * 32 + r31];

  float rs = 1e30f;
  int ri = 0x7fffffff;
  f32x16 acc[2][4] = {};
  half8 b0h[4], b0l[4], b1h[4], b1l[4];

  // prologue: B(0) into set 0
  {
    const size_t bt = (size_t)(split * 128) * 8192 + bbase;
#pragma unroll
    for (int ns = 0; ns < 4; ++ns) {
      b0h[ns] = *reinterpret_cast<const half8*>(CH + bt + ns * 1024);
      b0l[ns] = *reinterpret_cast<const half8*>(CL + bt + ns * 1024);
    }
  }

  auto step = [&](int u, half8 (&BH)[4], half8 (&BL)[4],
                  half8 (&NH)[4], half8 (&NL)[4]) {
    if (u + 1 < 128) {  // prefetch next step's B-frags into the other reg set
      const size_t bt = (size_t)(split * 128 + u + 1) * 8192 + bbase;
#pragma unroll
      for (int ns = 0; ns < 4; ++ns) {
        NH[ns] = *reinterpret_cast<const half8*>(CH + bt + ns * 1024);
        NL[ns] = *reinterpret_cast<const half8*>(CL + bt + ns * 1024);
      }
    }
    const size_t at = (size_t)(u & 31) * 4096 + abase;
    half8 ah[2], al[2];
#pragma unroll
    for (int ms = 0; ms < 2; ++ms) {
      ah[ms] = *reinterpret_cast<const half8*>(ZH + at + ms * 1024);
      al[ms] = *reinterpret_cast<const half8*>(ZL + at + ms * 1024);
    }
    // 3 product rounds of 8: each acc revisited every 8 MFMAs (no dep stall)
#pragma unroll
    for (int ms = 0; ms < 2; ++ms)
#pragma unroll
      for (int ns = 0; ns < 4; ++ns)
        acc[ms][ns] = __builtin_amdgcn_mfma_f32_32x32x16_f16(
            ah[ms], BH[ns], acc[ms][ns], 0, 0, 0);
#pragma unroll
    for (int ms = 0; ms < 2; ++ms)
#pragma unroll
      for (int ns = 0; ns < 4; ++ns)
        acc[ms][ns] = __builtin_amdgcn_mfma_f32_32x32x16_f16(
            ah[ms], BL[ns], acc[ms][ns], 0, 0, 0);
#pragma unroll
    for (int ms = 0; ms < 2; ++ms)
#pragma unroll
      for (int ns = 0; ns < 4; ++ns)
        acc[ms][ns] = __builtin_amdgcn_mfma_f32_32x32x16_f16(
            al[ms], BH[ns], acc[ms][ns], 0, 0, 0);
  };

  auto fold = [&](float c0, float c1, float c2, float c3, int pbase) {
    const int nlane = pbase + wn * 128 + r31;
#pragma unroll
    for (int ms = 0; ms < 2; ++ms)
#pragma unroll
      for (int r = 0; r < 16; ++r) {
        float s = c0 - 2.f * acc[ms][0][r];
        int ni = nlane;
        const float s1 = c1 - 2.f * acc[ms][1][r];
        if (s1 < s) { s = s1; ni = nlane + 32; }
        const float s2 = c2 - 2.f * acc[ms][2][r];
        if (s2 < s) { s = s2; ni = nlane + 64; }
        const float s3 = c3 - 2.f * acc[ms][3][r];
        if (s3 < s) { s = s3; ni = nlane + 96; }
#pragma unroll
        for (int off = 1; off <= 16; off <<= 1) {
          const float os = __shfl_xor(s, off);
          const int oi = __shfl_xor(ni, off);
          if (os < s || (os == s && oi < ni)) { s = os; ni = oi; }
        }
        if (r31 == ms * 16 + r) {
          if (s < rs || (s == rs && ni < ri)) { rs = s; ri = ni; }
        }
      }
#pragma unroll
    for (int ms = 0; ms < 2; ++ms)
#pragma unroll
      for (int ns = 0; ns < 4; ++ns) acc[ms][ns] = (f32x16)0.f;
  };

  for (int up = 0; up < 64; ++up) {
    step(2 * up, b0h, b0l, b1h, b1l);
    step(2 * up + 1, b1h, b1l, b0h, b0l);
    if ((up & 15) == 15) {
      const int pbase = split * 1024 + (up >> 4) * 256;
      switch (up >> 4) {
        case 0: fold(cs[0], cs[1], cs[2], cs[3], pbase); break;
        case 1: fold(cs[4], cs[5], cs[6], cs[7], pbase); break;
        case 2: fold(cs[8], cs[9], cs[10], cs[11], pbase); break;
        default: fold(cs[12], cs[13], cs[14], cs[15], pbase); break;
      }
    }
  }

  // each lane owns exactly one of the wave's 64 rows
  const int msL = r31 >> 4;
  const int rL = r31 & 15;
  const int grow = rowblk * 128 + wm * 64 + msL * 32 + (rL & 3) + 8 * (rL >> 2) + 4 * kh;
  partials[grow * SLOTS + split * 2 + wn] = make_float2(rs, (float)ri);
}

// ---------------- combine partial slots + gather codebook row ----------------
__global__ __launch_bounds__(128) void gather_kernel(const float* __restrict__ C,
                                                     const float2* __restrict__ partials,
                                                     float* __restrict__ zq,
                                                     float* __restrict__ idx_out) {
  const int b = blockIdx.x;
  float bsv = 1e30f;
  int bi = 0x7fffffff;
#pragma unroll
  for (int s = 0; s < SLOTS; ++s) {
    const float2 p = partials[b * SLOTS + s];
    const int i = (int)p.y;
    if (p.x < bsv || (p.x == bsv && i < bi)) { bsv = p.x; bi = i; }
  }
  const int t = threadIdx.x;
  const float4 v = *reinterpret_cast<const float4*>(C + (size_t)bi * Dn + t * 4);
  *reinterpret_cast<float4*>(zq + (size_t)b * Dn + t * 4) = v;
  if (t == 0) idx_out[b] = (float)bi;
}

extern "C" void kernel_launch(void* const* d_in, const int* in_sizes, int n_in,
                              void* d_out, int out_size, void* d_ws, size_t ws_size,
                              hipStream_t stream) {
  const float* Z = (const float*)d_in[0];  // [B, D]
  const float* C = (const float*)d_in[1];  // [K, D]
  float* out = (float*)d_out;              // [B*D] z_q then [B] indices

  char* ws = (char*)d_ws;                  // 34MB
  float* csq = (float*)(ws + WS_CSQ);
  float2* partials = (float2*)(ws + WS_PART);

  prep_kernel<<<4096, 256, 0, stream>>>(Z, C, ws);
  csq_kernel<<<Kn / 4, 256, 0, stream>>>(C, csq);
  vq_mfma<<<(Bn / 128) * 8, 256, 0, stream>>>(ws, csq, partials);
  gather_kernel<<<Bn, 128, 0, stream>>>(C, partials, out, out + (size_t)Bn * Dn);
}